// Round 1
// baseline (99.055 us; speedup 1.0000x reference)
//
#include <hip/hip_runtime.h>

// EquivariantDense: out[b, i*O4+o] = sum_j sum_k w_{j+1}[b,o,k] * x[b, ((i+j)%4)*K + k]
// B=8, O4=1024, K=4096, N=4*K=16384. Output (B, 4*O4) fp32.
// Memory-bound: 512 MiB of weights streamed once; x (512 KiB) is L2-resident.

#define B_DIM 8
#define O4_DIM 1024
#define K_DIM 4096
#define N_DIM 16384
#define TILE_O 4

__global__ __launch_bounds__(256) void eq_dense_kernel(
    const float* __restrict__ x,
    const float* __restrict__ w1,
    const float* __restrict__ w2,
    const float* __restrict__ w3,
    const float* __restrict__ w4,
    float* __restrict__ out)
{
    const int b    = blockIdx.y;
    const int o0   = blockIdx.x * TILE_O;
    const int tid  = threadIdx.x;
    const int j    = tid >> 6;   // wave id = which weight tensor
    const int lane = tid & 63;

    const float* wsel = (j == 0) ? w1 : (j == 1) ? w2 : (j == 2) ? w3 : w4;

    const float4* wrow[TILE_O];
#pragma unroll
    for (int o = 0; o < TILE_O; ++o)
        wrow[o] = reinterpret_cast<const float4*>(
            wsel + ((size_t)b * O4_DIM + (o0 + o)) * K_DIM);

    const float4* xq[4];
#pragma unroll
    for (int m = 0; m < 4; ++m)
        xq[m] = reinterpret_cast<const float4*>(
            x + (size_t)b * N_DIM + (size_t)m * K_DIM);

    float acc[TILE_O][4];
#pragma unroll
    for (int o = 0; o < TILE_O; ++o)
#pragma unroll
        for (int m = 0; m < 4; ++m)
            acc[o][m] = 0.0f;

    // K_DIM/4 = 1024 float4 per row; 64 lanes -> 16 iterations.
#pragma unroll 4
    for (int it = 0; it < 16; ++it) {
        const int idx = it * 64 + lane;
        float4 xv[4];
#pragma unroll
        for (int m = 0; m < 4; ++m)
            xv[m] = xq[m][idx];
#pragma unroll
        for (int o = 0; o < TILE_O; ++o) {
            const float4 wv = wrow[o][idx];
#pragma unroll
            for (int m = 0; m < 4; ++m) {
                acc[o][m] += wv.x * xv[m].x;
                acc[o][m] += wv.y * xv[m].y;
                acc[o][m] += wv.z * xv[m].z;
                acc[o][m] += wv.w * xv[m].w;
            }
        }
    }

    // Wave-level butterfly reduction of all 16 accumulators (64 lanes).
#pragma unroll
    for (int o = 0; o < TILE_O; ++o)
#pragma unroll
        for (int m = 0; m < 4; ++m) {
            float v = acc[o][m];
            v += __shfl_xor(v, 32, 64);
            v += __shfl_xor(v, 16, 64);
            v += __shfl_xor(v, 8, 64);
            v += __shfl_xor(v, 4, 64);
            v += __shfl_xor(v, 2, 64);
            v += __shfl_xor(v, 1, 64);
            acc[o][m] = v;
        }

    __shared__ float red[4][TILE_O][4];  // [j][o][m]
    if (lane == 0) {
#pragma unroll
        for (int o = 0; o < TILE_O; ++o)
#pragma unroll
            for (int m = 0; m < 4; ++m)
                red[j][o][m] = acc[o][m];
    }
    __syncthreads();

    // out[b, i*O4 + o0+o] = sum_j red[j][o][(i+j)&3]
    if (tid < TILE_O * 4) {
        const int o = tid & (TILE_O - 1);
        const int i = tid >> 2;
        float v = 0.0f;
#pragma unroll
        for (int jj = 0; jj < 4; ++jj)
            v += red[jj][o][(i + jj) & 3];
        out[(size_t)b * (4 * O4_DIM) + (size_t)i * O4_DIM + (o0 + o)] = v;
    }
}

extern "C" void kernel_launch(void* const* d_in, const int* in_sizes, int n_in,
                              void* d_out, int out_size, void* d_ws, size_t ws_size,
                              hipStream_t stream) {
    const float* x  = (const float*)d_in[0];
    const float* w1 = (const float*)d_in[1];
    const float* w2 = (const float*)d_in[2];
    const float* w3 = (const float*)d_in[3];
    const float* w4 = (const float*)d_in[4];
    float* out = (float*)d_out;

    dim3 grid(O4_DIM / TILE_O, B_DIM);  // (256, 8) = 2048 blocks
    dim3 block(256);
    eq_dense_kernel<<<grid, block, 0, stream>>>(x, w1, w2, w3, w4, out);
}